// Round 1
// baseline (49.045 us; speedup 1.0000x reference)
//
#include <hip/hip_runtime.h>
#include <math.h>

#define IMAGE_RES 128   // internal spatial res
#define FREQ_RES 64     // internal freq channels
#define FREQ_RES_OUT 16
#define IMG_OUT 64

__global__ __launch_bounds__(64) void cube_sim_kernel(
    const float* __restrict__ freqs,
    const float* __restrict__ p_incl,
    const float* __restrict__ p_rot,
    const float* __restrict__ p_lb,
    const float* __restrict__ p_vshift,
    const float* __restrict__ p_vmax,
    const float* __restrict__ p_rturn,
    const float* __restrict__ p_i0,
    const float* __restrict__ p_rd,
    const float* __restrict__ p_hz,
    float* __restrict__ out)
{
    const int t  = threadIdx.x;       // f channel 0..63
    const int xo = blockIdx.x;        // output x 0..63
    const int yo = blockIdx.y;        // output y 0..63

    // --- scalars (device-resident; each lane reads, cheap) ---
    const float incl   = p_incl[0];
    const float rot    = p_rot[0];
    const float lb     = p_lb[0];
    const float vshift = p_vshift[0];
    const float vmax   = p_vmax[0];
    const float rturn  = p_rturn[0];
    const float i0     = p_i0[0];
    const float rd     = p_rd[0];
    const float hz     = p_hz[0];

    const float ci = cosf(incl), si = sinf(incl);
    const float cr = cosf(rot),  sr = sinf(rot);

    // velocity label for this lane's f-channel, with systemic shift folded in
    const float C_KMS = 299792.458f;
    const float F0    = 230.538f;
    const float f_lo  = freqs[0];
    const float df    = (freqs[FREQ_RES_OUT - 1] - f_lo) / (float)(FREQ_RES - 1);
    const float fu    = f_lo + df * ((float)t - 2.0f);   // 0.5*FREQ_UPSCALE = 2
    const float vlf   = C_KMS * (F0 - fu) / F0 - vshift;

    const float inv_sig2 = 1.0f / (lb * lb);
    const float negc     = -inv_sig2 * 1.44269504088896f;  // * log2(e), for exp2
    const float scale    = 0.0625f / sqrtf(6.283185307179586f * lb * lb); // 1/16 pool * KDE norm

    // --- phase 1: per-(ixy, z) v_los and intensity into LDS ---
    __shared__ float2 s_vi[4][IMAGE_RES];   // {v_los, intensity}

    const float step = 2000.0f / 127.0f;
    const float inv_rturn = 1.0f / rturn;
    const float neg_inv_rd = -1.0f / rd;
    const float neg_inv_hz = -1.0f / hz;
    const float two_over_pi = 0.636619772367581f;

    for (int p = t; p < 4 * IMAGE_RES; p += 64) {
        const int ixy = p >> 7;           // 0..3 : (xi, yi)
        const int iz  = p & (IMAGE_RES - 1);
        const int xi  = ixy >> 1, yi = ixy & 1;
        const float x = -1000.0f + (float)(xo * 2 + xi) * step;
        const float y = -1000.0f + (float)(yo * 2 + yi) * step;
        const float z = -1000.0f + (float)iz * step;

        const float rx = cr * x - sr * y;          // z-independent
        const float u  = sr * x + cr * y;
        const float ry = ci * u - si * z;
        const float rz = si * u + ci * z;

        const float rad   = sqrtf(rx * rx + ry * ry + 1e-12f);
        const float v_abs = vmax * two_over_pi * atanf(rad * inv_rturn);
        const float vlos  = -si * v_abs * (rx / rad);
        const float inten = i0 * expf(rad * neg_inv_rd) * expf(fabsf(rz) * neg_inv_hz);

        s_vi[ixy][iz] = make_float2(vlos, inten);
    }
    __syncthreads();

    // --- phase 2: KDE accumulation over z for the 4 internal pixels ---
    float acc0 = 0.0f, acc1 = 0.0f, acc2 = 0.0f, acc3 = 0.0f;
    #pragma unroll 4
    for (int iz = 0; iz < IMAGE_RES; ++iz) {
        float2 a0 = s_vi[0][iz];
        float2 a1 = s_vi[1][iz];
        float2 a2 = s_vi[2][iz];
        float2 a3 = s_vi[3][iz];
        float d0 = vlf - a0.x;
        float d1 = vlf - a1.x;
        float d2 = vlf - a2.x;
        float d3 = vlf - a3.x;
        acc0 += exp2f(d0 * d0 * negc) * a0.y;
        acc1 += exp2f(d1 * d1 * negc) * a1.y;
        acc2 += exp2f(d2 * d2 * negc) * a2.y;
        acc3 += exp2f(d3 * d3 * negc) * a3.y;
    }

    // --- phase 3: pool over the 4 pixels and 4 freq sub-channels ---
    float s = (acc0 + acc1) + (acc2 + acc3);
    s += __shfl_xor(s, 1);
    s += __shfl_xor(s, 2);
    if ((t & 3) == 0) {
        const int fo = t >> 2;
        out[fo * (IMG_OUT * IMG_OUT) + xo * IMG_OUT + yo] = s * scale;
    }
}

extern "C" void kernel_launch(void* const* d_in, const int* in_sizes, int n_in,
                              void* d_out, int out_size, void* d_ws, size_t ws_size,
                              hipStream_t stream) {
    (void)in_sizes; (void)n_in; (void)d_ws; (void)ws_size; (void)out_size;
    const float* freqs    = (const float*)d_in[0];
    const float* incl     = (const float*)d_in[1];
    const float* rot      = (const float*)d_in[2];
    const float* lb       = (const float*)d_in[3];
    const float* vshift   = (const float*)d_in[4];
    const float* vmax     = (const float*)d_in[5];
    const float* rturn    = (const float*)d_in[6];
    const float* i0       = (const float*)d_in[7];
    const float* rd       = (const float*)d_in[8];
    const float* hz       = (const float*)d_in[9];
    float* out = (float*)d_out;

    dim3 grid(IMG_OUT, IMG_OUT);
    dim3 block(64);
    hipLaunchKernelGGL(cube_sim_kernel, grid, block, 0, stream,
                       freqs, incl, rot, lb, vshift, vmax, rturn, i0, rd, hz, out);
}